// Round 12
// baseline (374.380 us; speedup 1.0000x reference)
//
#include <hip/hip_runtime.h>

// ResNetBlock_MoE: B=64,C=64,H=W=56,E=8,TOPK=2. f32 in / f32 out.
// out = sum_k w_k*relu(bn2(conv2(relu(bn1(conv1(x,e)))))+x), plus dense_w.
//
// R23: R22 regressed (tap-minor concentrated L2 traffic -> hotspot; revert
// to kq-inner). R20-R22 lesson: compiler pins VGPR=64 and sinks prefetch
// loads -> ILP unattainable at source level. Fix is TLP: A-tile LDS (72KB)
// was capping occupancy at 2 blocks/CU (16 waves). A is 36KB/expert,
// L2-resident and line-shared by 4 waves/block -> read A fragments DIRECTLY
// from g_pw (global): conv1 has ZERO LDS, conv2 only 32KB combine buffer ->
// 4 blocks/CU = 32 waves/CU = 8 waves/SIMD (2x latency hiding; ~280cy of
// wave-interleaved issue covers L2 latency with no SW pipeline).
// __launch_bounds__(512,8) pins regalloc <=64 VGPR. stageA + its barrier
// gone; SGB dropped (null twice, fights the reg cap).
// Keeps: zero-page offset tables, SGPR plane bases, kq-plane activations,
// kq-inner slice order, barrier-free loop, XCD-chunked swizzle, A-reg
// rotation depth 3 (now from global), B depth 6, conv2 LDS combine.

#define BATCH 64
#define CH    64
#define HW_   3136            // 56*56
#define IMG_  (CH*HW_)        // 200704
#define PLANE (HW_*16)        // 50176 u16: one kq-plane [pos][ch16]
#define NE    8
#define JOBS  128
#define PWSZ  36864           // per-expert packed weights: 36*2mt*2h*32m*8j (u16)
#define NTILE 13              // ceil(3136/256) position tiles
#define BD    6               // B-prefetch depth in steps (x2 frags = 12 loads)
#define CGRID (NTILE*2*BATCH) // 1664 = 8 XCDs * 208

typedef unsigned short u16;
typedef __attribute__((ext_vector_type(8))) short short8_t;   // 8 bf16 = 4 VGPR
typedef __attribute__((ext_vector_type(16))) float floatx16;  // 32x32 MFMA acc

// +4*PLANE zero tails (never written; .bss zero-init) back the invalid-tap
// offsets: any off in [zoff, zoff+3*PLANE*2+16] reads zeros.
__device__ u16   g_xb[(size_t)BATCH*IMG_ + 4*PLANE];  // x bf16 [b][kq][pos][ch16]
__device__ u16   g_h[(size_t)JOBS*IMG_ + 4*PLANE];    // conv1 out [job][kq][pos][ch16]
__device__ u16   g_pw1[NE * PWSZ];            // packed conv1 w (bn1_s folded)
__device__ u16   g_pw2[NE * PWSZ];            // packed conv2 w (bn2_s folded)
__device__ int   g_eid[JOBS];
__device__ float g_wgt[JOBS];
__device__ float g_pool[49 * BATCH * CH];     // GAP partials [tile49][b][ch]

__device__ __forceinline__ u16 f2b(float f) {
    unsigned v; __builtin_memcpy(&v, &f, 4);
    return (u16)((v + 0x7FFFu + ((v >> 16) & 1u)) >> 16);   // RNE
}

// ---------------- fused prep: pack + xconv (independent outputs) ------------
// grid = 2304 (pack) + 3136 (xconv) blocks of 256. No atomics, no fences.
// pack: s36 = tap*4 + kq (kq-INNER, R21 order), ci = kq*16 + h*8 + j.
__global__ __launch_bounds__(256) void prep_kernel(
    const float* __restrict__ x,
    const float* __restrict__ w1, const float* __restrict__ s1,
    const float* __restrict__ w2, const float* __restrict__ s2)
{
    int bid = blockIdx.x;
    int tid = threadIdx.x;
    if (bid < 2304) {                       // ---- pack (whole block) ----
        int idx = bid * 256 + tid;          // < 589824
        int conv = idx / 294912;
        int i2 = idx - conv * 294912;
        int e = i2 / PWSZ;   int r = i2 - e * PWSZ;
        int s36 = r >> 10;   int r2 = r & 1023;
        int mt  = r2 >> 9;   int r3 = r2 & 511;
        int h   = r3 >> 8;   int r4 = r3 & 255;
        int m   = r4 >> 3;   int j  = r4 & 7;
        int tap = s36 >> 2;
        int ci  = ((s36 & 3) << 4) | (h << 3) | j;
        int M   = mt*32 + m;
        const float* w  = conv ? w2 : w1;
        const float* sc = conv ? s2 : s1;
        float v = w[((e*64 + M)*64 + ci)*9 + tap] * sc[e*64 + M];
        (conv ? g_pw2 : g_pw1)[i2] = f2b(v);
        return;
    }
    // ---- xconv: x NCHW f32 -> g_xb [kq][pos][ch16] bf16 + GAP partial ----
    __shared__ u16 T[64*66];                // [pos][ch], stride 66
    int xid = bid - 2304;
    int b = xid / 49;
    int tile = xid - b*49;
    int pos0 = tile * 64;
    int pin = tid & 63;
    int c0 = tid >> 6;                      // 0..3
    const float* xb = x + (size_t)b*IMG_ + pos0 + pin;
    #pragma unroll
    for (int i = 0; i < 16; i++) {
        int ch = c0*16 + i;
        T[pin*66 + ch] = f2b(xb[ch*HW_]);   // coalesced 256B f32 read per instr
    }
    __syncthreads();
    u16* ob = g_xb + (size_t)b*IMG_ + (size_t)pos0*16;   // within-plane offset
    #pragma unroll
    for (int i = 0; i < 16; i++) {
        int j = tid + i*256;                // 0..4095
        int kq  = j >> 10;
        int pos = (j >> 4) & 63;
        int c16 = j & 15;
        ob[(size_t)kq*PLANE + pos*16 + c16] = T[pos*66 + kq*16 + c16];
    }
    // GAP partial: threads 0..63 sum their channel over the 64 positions.
    if (tid < 64) {
        float s = 0.f;
        const float* xc = x + (size_t)b*IMG_ + tid*HW_ + pos0;
        #pragma unroll 4
        for (int p = 0; p < 64; p++) s += xc[p];
        g_pool[tile*(BATCH*CH) + b*64 + tid] = s;
    }
}

// ---------------- gate finalize: pool -> logits -> top2 softmax -------------
__global__ __launch_bounds__(64) void gate_fin_kernel(
    const float* __restrict__ gw, const float* __restrict__ gb,
    float* __restrict__ dw_out)
{
    __shared__ float pooled[CH];
    __shared__ float logits[NE];
    int b = blockIdx.x, t = threadIdx.x;
    float s = 0.f;
    #pragma unroll
    for (int i = 0; i < 49; i++) s += g_pool[i*(BATCH*CH) + b*64 + t];
    pooled[t] = s * (1.f/3136.f);
    __syncthreads();
    if (t < NE) {
        float l = gb[t];
        for (int c = 0; c < CH; c++) l += pooled[c] * gw[t*CH + c];
        logits[t] = l;
    }
    __syncthreads();
    if (t == 0) {
        int i1 = 0; float v1 = logits[0];
        for (int e = 1; e < NE; e++) if (logits[e] > v1) { v1 = logits[e]; i1 = e; }
        int i2 = -1; float v2 = -3.4e38f;
        for (int e = 0; e < NE; e++) if (e != i1 && logits[e] > v2) { v2 = logits[e]; i2 = e; }
        float eb = __expf(v2 - v1);
        float wa = 1.f / (1.f + eb), wb = eb / (1.f + eb);
        for (int e = 0; e < NE; e++) dw_out[b*NE + e] = 0.f;
        dw_out[b*NE + i1] = wa;
        dw_out[b*NE + i2] = wb;
        g_eid[2*b] = i1; g_eid[2*b+1] = i2;
        g_wgt[2*b] = wa; g_wgt[2*b+1] = wb;
    }
}

// Per-tap offset tables: valid -> p*32 + h*16 bytes within the kq-plane;
// invalid -> zoff (zero tail past the image array).
__device__ __forceinline__ void mkOffs(
    unsigned* off, int gn, int y, int xc, int h, unsigned zoff)
{
    #pragma unroll
    for (int tap = 0; tap < 9; tap++) {
        int dy = tap/3 - 1, dx = tap - (tap/3)*3 - 1;
        int p = gn + dy*56 + dx;
        bool vld = ((unsigned)(y + dy) < 56u) && ((unsigned)(xc + dx) < 56u);
        off[tap] = vld ? (unsigned)(p*32 + h*16) : zoff;
    }
}
#define LOADB(bk, off) (*(const short8_t*)((bk) + (off)))

// ---------------- conv1 + bn1 + relu -> g_h ---------------------------------
// ZERO LDS; A fragments read directly from g_pw (L2-hot 36KB/expert, line-
// shared by 4 waves/block). 8 waves/SIMD occupancy does the latency hiding.
// 1D grid 1664, XCD-chunked decode: L = (wg&7)*208 + wg/8.
__global__ __launch_bounds__(512, 8) void conv1_kernel(const float* __restrict__ b1)
{
    int wg = blockIdx.x;
    int L  = (wg & 7) * (CGRID/8) + (wg >> 3);
    int b  = L / 26;
    int r  = L - b*26;
    int tile = r >> 1;
    int mt   = r & 1;
    int e0 = g_eid[2*b], e1 = g_eid[2*b+1];
    int tid = threadIdx.x;
    int lane = tid & 63, w = tid >> 6;  // 8 waves
    int es = w & 1, pg = w >> 1;        // expert slot (2), position group (4)
    int l31 = lane & 31, h = lane >> 5;
    int gn0 = tile*256 + pg*64 + l31;   // frag 0 position (may be >= 3136)
    int gn1 = gn0 + 32;                 // frag 1 position
    int y0 = gn0/56, xc0 = gn0 - y0*56;
    int y1 = gn1/56, xc1 = gn1 - y1*56;
    int e = es ? e1 : e0;
    const char* base = (const char*)(g_xb + (size_t)b*IMG_);
    const char* bk0 = base;                      // uniform SGPR plane bases
    const char* bk1 = base + PLANE*2;
    const char* bk2 = base + 2*PLANE*2;
    const char* bk3 = base + 3*PLANE*2;
    unsigned zoff = (unsigned)((size_t)(BATCH - b)*IMG_*2);
    // per-wave A stream: [s36][mt][h][m][j]; wave reads 1KB contiguous/step
    const u16* pwA = g_pw1 + e*PWSZ + mt*512 + h*256 + l31*8;   // + s*1024

    unsigned off0[9], off1[9];
    mkOffs(off0, gn0, y0, xc0, h, zoff);
    mkOffs(off1, gn1, y1, xc1, h, zoff);

    floatx16 accA = {}, accB = {};      // frag 0 / frag 1 accumulators
    short8_t B0[BD], B1[BD];
    #pragma unroll
    for (int s = 0; s < BD; s++) {      // kq-inner: bk=(s&3), tap=s>>2
        const char* bk = (s&3)==0 ? bk0 : (s&3)==1 ? bk1 : (s&3)==2 ? bk2 : bk3;
        B0[s] = LOADB(bk, off0[s >> 2]);
        B1[s] = LOADB(bk, off1[s >> 2]);
    }
    short8_t Ar[3];                     // A rotation depth 3 (global, L2-hot)
    #pragma unroll
    for (int i = 0; i < 3; i++)
        Ar[i] = *(const short8_t*)(pwA + i*1024);

    #pragma unroll
    for (int s = 0; s < 36; s++) {
        short8_t bb0 = B0[s % BD];      // capture BEFORE refill
        short8_t bb1 = B1[s % BD];
        int sp = s + BD;
        if (sp < 36) {                  // refill: bare saddr+voffset loads
            const char* bk = (sp&3)==0 ? bk0 : (sp&3)==1 ? bk1 : (sp&3)==2 ? bk2 : bk3;
            B0[s % BD] = LOADB(bk, off0[sp >> 2]);
            B1[s % BD] = LOADB(bk, off1[sp >> 2]);
        }
        short8_t a = Ar[s % 3];
        if (s + 3 < 36)
            Ar[s % 3] = *(const short8_t*)(pwA + (s+3)*1024);
        accA = __builtin_amdgcn_mfma_f32_32x32x16_bf16(a, bb0, accA, 0, 0, 0);
        accB = __builtin_amdgcn_mfma_f32_32x32x16_bf16(a, bb1, accB, 0, 0, 0);
    }

    // epilogue -> g_h [kq][pos][ch16]: kq = mt*2 + (rg>>1), c = (rg&1)*8 + h*4
    u16* hb = g_h + (size_t)(2*b + es)*IMG_;
    #pragma unroll
    for (int f = 0; f < 2; f++) {
        int gn = f ? gn1 : gn0;
        if (gn < HW_) {
            #pragma unroll
            for (int rg = 0; rg < 4; rg++) {
                union { u16 u[4]; uint2 v; } t;
                #pragma unroll
                for (int rr = 0; rr < 4; rr++) {
                    int m = rg*8 + h*4 + rr;       // D row = (reg&3)+8*(reg>>2)+4*h
                    float v = (f ? accB : accA)[rg*4 + rr] + b1[e*64 + mt*32 + m];
                    t.u[rr] = f2b(fmaxf(v, 0.f));
                }
                int kq = mt*2 + (rg >> 1);
                *(uint2*)(hb + (size_t)kq*PLANE + (size_t)gn*16 + (rg & 1)*8 + h*4) = t.v;
            }
        }
    }
}

// ---------------- conv2 + bn2 + residual + cross-wave combine ---------------
__global__ __launch_bounds__(512, 8) void conv2_kernel(
    const float* __restrict__ x, const float* __restrict__ b2,
    float* __restrict__ out)
{
    __shared__ float P[8192];           // 32KB combine buffer (only LDS here)
    int wg = blockIdx.x;
    int L  = (wg & 7) * (CGRID/8) + (wg >> 3);
    int b  = L / 26;                    // SAME b->XCD map as conv1 (h L2 reuse)
    int r  = L - b*26;
    int tile = (NTILE-1) - (r >> 1);    // tile-LIFO within b (newest h first)
    int mt   = r & 1;
    int e0 = g_eid[2*b], e1 = g_eid[2*b+1];
    int tid = threadIdx.x;
    int lane = tid & 63, w = tid >> 6;
    int es = w & 1, pg = w >> 1;
    int l31 = lane & 31, h = lane >> 5;
    int gn0 = tile*256 + pg*64 + l31;
    int gn1 = gn0 + 32;
    int y0 = gn0/56, xc0 = gn0 - y0*56;
    int y1 = gn1/56, xc1 = gn1 - y1*56;
    int e = es ? e1 : e0;
    float wgt = g_wgt[2*b + es];
    const char* base = (const char*)(g_h + (size_t)(2*b + es)*IMG_);
    const char* bk0 = base;
    const char* bk1 = base + PLANE*2;
    const char* bk2 = base + 2*PLANE*2;
    const char* bk3 = base + 3*PLANE*2;
    unsigned zoff = (unsigned)((size_t)(JOBS - (2*b + es))*IMG_*2);
    const u16* pwA = g_pw2 + e*PWSZ + mt*512 + h*256 + l31*8;

    unsigned off0[9], off1[9];
    mkOffs(off0, gn0, y0, xc0, h, zoff);
    mkOffs(off1, gn1, y1, xc1, h, zoff);

    floatx16 accA = {}, accB = {};
    short8_t B0[BD], B1[BD];
    #pragma unroll
    for (int s = 0; s < BD; s++) {
        const char* bk = (s&3)==0 ? bk0 : (s&3)==1 ? bk1 : (s&3)==2 ? bk2 : bk3;
        B0[s] = LOADB(bk, off0[s >> 2]);
        B1[s] = LOADB(bk, off1[s >> 2]);
    }
    short8_t Ar[3];
    #pragma unroll
    for (int i = 0; i < 3; i++)
        Ar[i] = *(const short8_t*)(pwA + i*1024);

    #pragma unroll
    for (int s = 0; s < 36; s++) {
        short8_t bb0 = B0[s % BD];      // capture BEFORE refill
        short8_t bb1 = B1[s % BD];
        int sp = s + BD;
        if (sp < 36) {
            const char* bk = (sp&3)==0 ? bk0 : (sp&3)==1 ? bk1 : (sp&3)==2 ? bk2 : bk3;
            B0[s % BD] = LOADB(bk, off0[sp >> 2]);
            B1[s % BD] = LOADB(bk, off1[sp >> 2]);
        }
        short8_t a = Ar[s % 3];
        if (s + 3 < 36)
            Ar[s % 3] = *(const short8_t*)(pwA + (s+3)*1024);
        accA = __builtin_amdgcn_mfma_f32_32x32x16_bf16(a, bb0, accA, 0, 0, 0);
        accB = __builtin_amdgcn_mfma_f32_32x32x16_bf16(a, bb1, accB, 0, 0, 0);
    }

    // combine: es0 waves drop w0*relu(y0+x) into LDS, es1 waves add+store.
    const float* xb = x + (size_t)b*IMG_ + (size_t)(mt*32)*HW_;
    if (es == 0) {
        #pragma unroll
        for (int f = 0; f < 2; f++) {
            int gn = f ? gn1 : gn0;
            if (gn < HW_) {
                #pragma unroll
                for (int rg = 0; rg < 4; rg++)
                    #pragma unroll
                    for (int rr = 0; rr < 4; rr++) {
                        int m = rg*8 + h*4 + rr;
                        float v = (f ? accB : accA)[rg*4 + rr] + b2[e*64 + mt*32 + m]
                                  + xb[(size_t)m*HW_ + gn];
                        P[((pg*2 + f)*32 + m)*32 + l31] = wgt * fmaxf(v, 0.f);
                    }
            }
        }
    }
    __syncthreads();
    if (es == 1) {
        float* ob = out + (size_t)b*IMG_ + (size_t)(mt*32)*HW_;
        #pragma unroll
        for (int f = 0; f < 2; f++) {
            int gn = f ? gn1 : gn0;
            if (gn < HW_) {
                #pragma unroll
                for (int rg = 0; rg < 4; rg++)
                    #pragma unroll
                    for (int rr = 0; rr < 4; rr++) {
                        int m = rg*8 + h*4 + rr;
                        float v = (f ? accB : accA)[rg*4 + rr] + b2[e*64 + mt*32 + m]
                                  + xb[(size_t)m*HW_ + gn];
                        ob[(size_t)m*HW_ + gn] = wgt * fmaxf(v, 0.f)
                                                 + P[((pg*2 + f)*32 + m)*32 + l31];
                    }
            }
        }
    }
}

extern "C" void kernel_launch(void* const* d_in, const int* in_sizes, int n_in,
                              void* d_out, int out_size, void* d_ws, size_t ws_size,
                              hipStream_t stream) {
    const float* x   = (const float*)d_in[0];
    const float* gw  = (const float*)d_in[1];
    const float* gb  = (const float*)d_in[2];
    const float* w1  = (const float*)d_in[3];
    const float* s1  = (const float*)d_in[4];
    const float* b1  = (const float*)d_in[5];
    const float* w2  = (const float*)d_in[6];
    const float* s2  = (const float*)d_in[7];
    const float* b2  = (const float*)d_in[8];
    float* out = (float*)d_out;
    float* dw  = out + (size_t)BATCH * IMG_;   // dense_w region of d_out (f32)

    (void)d_ws; (void)ws_size;                 // zero d_ws usage (R1/R2 aborts)

    hipLaunchKernelGGL(prep_kernel, dim3(2304 + 3136), dim3(256), 0, stream,
                       x, w1, s1, w2, s2);
    hipLaunchKernelGGL(gate_fin_kernel, dim3(BATCH), dim3(64), 0, stream, gw, gb, dw);
    hipLaunchKernelGGL(conv1_kernel, dim3(CGRID), dim3(512), 0, stream, b1);
    hipLaunchKernelGGL(conv2_kernel, dim3(CGRID), dim3(512), 0, stream, x, b2, out);
}

// Round 13
// 260.413 us; speedup vs baseline: 1.4376x; 1.4376x over previous
//
#include <hip/hip_runtime.h>

// ResNetBlock_MoE: B=64,C=64,H=W=56,E=8,TOPK=2. f32 in / f32 out.
// out = sum_k w_k*relu(bn2(conv2(relu(bn1(conv1(x,e)))))+x), plus dense_w.
//
// R24: R23 post-mortem — __launch_bounds__(512,8) demanded <=64 VGPR; live
// state (32 acc + 48 B + offsets) doesn't fit -> compiler SPILLED acc to
// scratch (VGPR=32, FETCH 238MB, WRITE 243MB, conv2 200us). Same structure,
// launch_bounds(512,4): natural reg budget (settles ~64-96, no spill);
// occupancy is then LDS-freed: conv1 0 LDS, conv2 32KB -> 4 blocks/CU =
// 32 waves/CU (2x R21's TLP) while VGPR<=64 permits 8 waves/SIMD.
// Keeps: A direct from g_pw (36KB/expert, L2-hot, 4-way line-shared),
// zero-page offset tables, SGPR plane bases, kq-plane activations, kq-inner
// slice order, barrier-free loop, XCD-chunked swizzle, A-reg rotation 3,
// B depth 6, conv2 LDS combine, 4-launch structure.

#define BATCH 64
#define CH    64
#define HW_   3136            // 56*56
#define IMG_  (CH*HW_)        // 200704
#define PLANE (HW_*16)        // 50176 u16: one kq-plane [pos][ch16]
#define NE    8
#define JOBS  128
#define PWSZ  36864           // per-expert packed weights: 36*2mt*2h*32m*8j (u16)
#define NTILE 13              // ceil(3136/256) position tiles
#define BD    6               // B-prefetch depth in steps (x2 frags = 12 loads)
#define CGRID (NTILE*2*BATCH) // 1664 = 8 XCDs * 208

typedef unsigned short u16;
typedef __attribute__((ext_vector_type(8))) short short8_t;   // 8 bf16 = 4 VGPR
typedef __attribute__((ext_vector_type(16))) float floatx16;  // 32x32 MFMA acc

// +4*PLANE zero tails (never written; .bss zero-init) back the invalid-tap
// offsets: any off in [zoff, zoff+3*PLANE*2+16] reads zeros.
__device__ u16   g_xb[(size_t)BATCH*IMG_ + 4*PLANE];  // x bf16 [b][kq][pos][ch16]
__device__ u16   g_h[(size_t)JOBS*IMG_ + 4*PLANE];    // conv1 out [job][kq][pos][ch16]
__device__ u16   g_pw1[NE * PWSZ];            // packed conv1 w (bn1_s folded)
__device__ u16   g_pw2[NE * PWSZ];            // packed conv2 w (bn2_s folded)
__device__ int   g_eid[JOBS];
__device__ float g_wgt[JOBS];
__device__ float g_pool[49 * BATCH * CH];     // GAP partials [tile49][b][ch]

__device__ __forceinline__ u16 f2b(float f) {
    unsigned v; __builtin_memcpy(&v, &f, 4);
    return (u16)((v + 0x7FFFu + ((v >> 16) & 1u)) >> 16);   // RNE
}

// ---------------- fused prep: pack + xconv (independent outputs) ------------
// grid = 2304 (pack) + 3136 (xconv) blocks of 256. No atomics, no fences.
// pack: s36 = tap*4 + kq (kq-INNER), ci = kq*16 + h*8 + j.
__global__ __launch_bounds__(256) void prep_kernel(
    const float* __restrict__ x,
    const float* __restrict__ w1, const float* __restrict__ s1,
    const float* __restrict__ w2, const float* __restrict__ s2)
{
    int bid = blockIdx.x;
    int tid = threadIdx.x;
    if (bid < 2304) {                       // ---- pack (whole block) ----
        int idx = bid * 256 + tid;          // < 589824
        int conv = idx / 294912;
        int i2 = idx - conv * 294912;
        int e = i2 / PWSZ;   int r = i2 - e * PWSZ;
        int s36 = r >> 10;   int r2 = r & 1023;
        int mt  = r2 >> 9;   int r3 = r2 & 511;
        int h   = r3 >> 8;   int r4 = r3 & 255;
        int m   = r4 >> 3;   int j  = r4 & 7;
        int tap = s36 >> 2;
        int ci  = ((s36 & 3) << 4) | (h << 3) | j;
        int M   = mt*32 + m;
        const float* w  = conv ? w2 : w1;
        const float* sc = conv ? s2 : s1;
        float v = w[((e*64 + M)*64 + ci)*9 + tap] * sc[e*64 + M];
        (conv ? g_pw2 : g_pw1)[i2] = f2b(v);
        return;
    }
    // ---- xconv: x NCHW f32 -> g_xb [kq][pos][ch16] bf16 + GAP partial ----
    __shared__ u16 T[64*66];                // [pos][ch], stride 66
    int xid = bid - 2304;
    int b = xid / 49;
    int tile = xid - b*49;
    int pos0 = tile * 64;
    int pin = tid & 63;
    int c0 = tid >> 6;                      // 0..3
    const float* xb = x + (size_t)b*IMG_ + pos0 + pin;
    #pragma unroll
    for (int i = 0; i < 16; i++) {
        int ch = c0*16 + i;
        T[pin*66 + ch] = f2b(xb[ch*HW_]);   // coalesced 256B f32 read per instr
    }
    __syncthreads();
    u16* ob = g_xb + (size_t)b*IMG_ + (size_t)pos0*16;   // within-plane offset
    #pragma unroll
    for (int i = 0; i < 16; i++) {
        int j = tid + i*256;                // 0..4095
        int kq  = j >> 10;
        int pos = (j >> 4) & 63;
        int c16 = j & 15;
        ob[(size_t)kq*PLANE + pos*16 + c16] = T[pos*66 + kq*16 + c16];
    }
    // GAP partial: threads 0..63 sum their channel over the 64 positions.
    if (tid < 64) {
        float s = 0.f;
        const float* xc = x + (size_t)b*IMG_ + tid*HW_ + pos0;
        #pragma unroll 4
        for (int p = 0; p < 64; p++) s += xc[p];
        g_pool[tile*(BATCH*CH) + b*64 + tid] = s;
    }
}

// ---------------- gate finalize: pool -> logits -> top2 softmax -------------
__global__ __launch_bounds__(64) void gate_fin_kernel(
    const float* __restrict__ gw, const float* __restrict__ gb,
    float* __restrict__ dw_out)
{
    __shared__ float pooled[CH];
    __shared__ float logits[NE];
    int b = blockIdx.x, t = threadIdx.x;
    float s = 0.f;
    #pragma unroll
    for (int i = 0; i < 49; i++) s += g_pool[i*(BATCH*CH) + b*64 + t];
    pooled[t] = s * (1.f/3136.f);
    __syncthreads();
    if (t < NE) {
        float l = gb[t];
        for (int c = 0; c < CH; c++) l += pooled[c] * gw[t*CH + c];
        logits[t] = l;
    }
    __syncthreads();
    if (t == 0) {
        int i1 = 0; float v1 = logits[0];
        for (int e = 1; e < NE; e++) if (logits[e] > v1) { v1 = logits[e]; i1 = e; }
        int i2 = -1; float v2 = -3.4e38f;
        for (int e = 0; e < NE; e++) if (e != i1 && logits[e] > v2) { v2 = logits[e]; i2 = e; }
        float eb = __expf(v2 - v1);
        float wa = 1.f / (1.f + eb), wb = eb / (1.f + eb);
        for (int e = 0; e < NE; e++) dw_out[b*NE + e] = 0.f;
        dw_out[b*NE + i1] = wa;
        dw_out[b*NE + i2] = wb;
        g_eid[2*b] = i1; g_eid[2*b+1] = i2;
        g_wgt[2*b] = wa; g_wgt[2*b+1] = wb;
    }
}

// Per-tap offset tables: valid -> p*32 + h*16 bytes within the kq-plane;
// invalid -> zoff (zero tail past the image array).
__device__ __forceinline__ void mkOffs(
    unsigned* off, int gn, int y, int xc, int h, unsigned zoff)
{
    #pragma unroll
    for (int tap = 0; tap < 9; tap++) {
        int dy = tap/3 - 1, dx = tap - (tap/3)*3 - 1;
        int p = gn + dy*56 + dx;
        bool vld = ((unsigned)(y + dy) < 56u) && ((unsigned)(xc + dx) < 56u);
        off[tap] = vld ? (unsigned)(p*32 + h*16) : zoff;
    }
}
#define LOADB(bk, off) (*(const short8_t*)((bk) + (off)))

// ---------------- conv1 + bn1 + relu -> g_h ---------------------------------
// ZERO LDS; A fragments read directly from g_pw (L2-hot 36KB/expert, line-
// shared by 4 waves/block). Occupancy freed by LDS -> up to 4 blocks/CU.
// 1D grid 1664, XCD-chunked decode: L = (wg&7)*208 + wg/8.
__global__ __launch_bounds__(512, 4) void conv1_kernel(const float* __restrict__ b1)
{
    int wg = blockIdx.x;
    int L  = (wg & 7) * (CGRID/8) + (wg >> 3);
    int b  = L / 26;
    int r  = L - b*26;
    int tile = r >> 1;
    int mt   = r & 1;
    int e0 = g_eid[2*b], e1 = g_eid[2*b+1];
    int tid = threadIdx.x;
    int lane = tid & 63, w = tid >> 6;  // 8 waves
    int es = w & 1, pg = w >> 1;        // expert slot (2), position group (4)
    int l31 = lane & 31, h = lane >> 5;
    int gn0 = tile*256 + pg*64 + l31;   // frag 0 position (may be >= 3136)
    int gn1 = gn0 + 32;                 // frag 1 position
    int y0 = gn0/56, xc0 = gn0 - y0*56;
    int y1 = gn1/56, xc1 = gn1 - y1*56;
    int e = es ? e1 : e0;
    const char* base = (const char*)(g_xb + (size_t)b*IMG_);
    const char* bk0 = base;                      // uniform SGPR plane bases
    const char* bk1 = base + PLANE*2;
    const char* bk2 = base + 2*PLANE*2;
    const char* bk3 = base + 3*PLANE*2;
    unsigned zoff = (unsigned)((size_t)(BATCH - b)*IMG_*2);
    // per-wave A stream: [s36][mt][h][m][j]; wave reads 1KB contiguous/step
    const u16* pwA = g_pw1 + e*PWSZ + mt*512 + h*256 + l31*8;   // + s*1024

    unsigned off0[9], off1[9];
    mkOffs(off0, gn0, y0, xc0, h, zoff);
    mkOffs(off1, gn1, y1, xc1, h, zoff);

    floatx16 accA = {}, accB = {};      // frag 0 / frag 1 accumulators
    short8_t B0[BD], B1[BD];
    #pragma unroll
    for (int s = 0; s < BD; s++) {      // kq-inner: bk=(s&3), tap=s>>2
        const char* bk = (s&3)==0 ? bk0 : (s&3)==1 ? bk1 : (s&3)==2 ? bk2 : bk3;
        B0[s] = LOADB(bk, off0[s >> 2]);
        B1[s] = LOADB(bk, off1[s >> 2]);
    }
    short8_t Ar[3];                     // A rotation depth 3 (global, L2-hot)
    #pragma unroll
    for (int i = 0; i < 3; i++)
        Ar[i] = *(const short8_t*)(pwA + i*1024);

    #pragma unroll
    for (int s = 0; s < 36; s++) {
        short8_t bb0 = B0[s % BD];      // capture BEFORE refill
        short8_t bb1 = B1[s % BD];
        int sp = s + BD;
        if (sp < 36) {                  // refill: bare saddr+voffset loads
            const char* bk = (sp&3)==0 ? bk0 : (sp&3)==1 ? bk1 : (sp&3)==2 ? bk2 : bk3;
            B0[s % BD] = LOADB(bk, off0[sp >> 2]);
            B1[s % BD] = LOADB(bk, off1[sp >> 2]);
        }
        short8_t a = Ar[s % 3];
        if (s + 3 < 36)
            Ar[s % 3] = *(const short8_t*)(pwA + (s+3)*1024);
        accA = __builtin_amdgcn_mfma_f32_32x32x16_bf16(a, bb0, accA, 0, 0, 0);
        accB = __builtin_amdgcn_mfma_f32_32x32x16_bf16(a, bb1, accB, 0, 0, 0);
    }

    // epilogue -> g_h [kq][pos][ch16]: kq = mt*2 + (rg>>1), c = (rg&1)*8 + h*4
    u16* hb = g_h + (size_t)(2*b + es)*IMG_;
    #pragma unroll
    for (int f = 0; f < 2; f++) {
        int gn = f ? gn1 : gn0;
        if (gn < HW_) {
            #pragma unroll
            for (int rg = 0; rg < 4; rg++) {
                union { u16 u[4]; uint2 v; } t;
                #pragma unroll
                for (int rr = 0; rr < 4; rr++) {
                    int m = rg*8 + h*4 + rr;       // D row = (reg&3)+8*(reg>>2)+4*h
                    float v = (f ? accB : accA)[rg*4 + rr] + b1[e*64 + mt*32 + m];
                    t.u[rr] = f2b(fmaxf(v, 0.f));
                }
                int kq = mt*2 + (rg >> 1);
                *(uint2*)(hb + (size_t)kq*PLANE + (size_t)gn*16 + (rg & 1)*8 + h*4) = t.v;
            }
        }
    }
}

// ---------------- conv2 + bn2 + residual + cross-wave combine ---------------
__global__ __launch_bounds__(512, 4) void conv2_kernel(
    const float* __restrict__ x, const float* __restrict__ b2,
    float* __restrict__ out)
{
    __shared__ float P[8192];           // 32KB combine buffer (only LDS here)
    int wg = blockIdx.x;
    int L  = (wg & 7) * (CGRID/8) + (wg >> 3);
    int b  = L / 26;                    // SAME b->XCD map as conv1 (h L2 reuse)
    int r  = L - b*26;
    int tile = (NTILE-1) - (r >> 1);    // tile-LIFO within b (newest h first)
    int mt   = r & 1;
    int e0 = g_eid[2*b], e1 = g_eid[2*b+1];
    int tid = threadIdx.x;
    int lane = tid & 63, w = tid >> 6;
    int es = w & 1, pg = w >> 1;
    int l31 = lane & 31, h = lane >> 5;
    int gn0 = tile*256 + pg*64 + l31;
    int gn1 = gn0 + 32;
    int y0 = gn0/56, xc0 = gn0 - y0*56;
    int y1 = gn1/56, xc1 = gn1 - y1*56;
    int e = es ? e1 : e0;
    float wgt = g_wgt[2*b + es];
    const char* base = (const char*)(g_h + (size_t)(2*b + es)*IMG_);
    const char* bk0 = base;
    const char* bk1 = base + PLANE*2;
    const char* bk2 = base + 2*PLANE*2;
    const char* bk3 = base + 3*PLANE*2;
    unsigned zoff = (unsigned)((size_t)(JOBS - (2*b + es))*IMG_*2);
    const u16* pwA = g_pw2 + e*PWSZ + mt*512 + h*256 + l31*8;

    unsigned off0[9], off1[9];
    mkOffs(off0, gn0, y0, xc0, h, zoff);
    mkOffs(off1, gn1, y1, xc1, h, zoff);

    floatx16 accA = {}, accB = {};
    short8_t B0[BD], B1[BD];
    #pragma unroll
    for (int s = 0; s < BD; s++) {
        const char* bk = (s&3)==0 ? bk0 : (s&3)==1 ? bk1 : (s&3)==2 ? bk2 : bk3;
        B0[s] = LOADB(bk, off0[s >> 2]);
        B1[s] = LOADB(bk, off1[s >> 2]);
    }
    short8_t Ar[3];
    #pragma unroll
    for (int i = 0; i < 3; i++)
        Ar[i] = *(const short8_t*)(pwA + i*1024);

    #pragma unroll
    for (int s = 0; s < 36; s++) {
        short8_t bb0 = B0[s % BD];      // capture BEFORE refill
        short8_t bb1 = B1[s % BD];
        int sp = s + BD;
        if (sp < 36) {
            const char* bk = (sp&3)==0 ? bk0 : (sp&3)==1 ? bk1 : (sp&3)==2 ? bk2 : bk3;
            B0[s % BD] = LOADB(bk, off0[sp >> 2]);
            B1[s % BD] = LOADB(bk, off1[sp >> 2]);
        }
        short8_t a = Ar[s % 3];
        if (s + 3 < 36)
            Ar[s % 3] = *(const short8_t*)(pwA + (s+3)*1024);
        accA = __builtin_amdgcn_mfma_f32_32x32x16_bf16(a, bb0, accA, 0, 0, 0);
        accB = __builtin_amdgcn_mfma_f32_32x32x16_bf16(a, bb1, accB, 0, 0, 0);
    }

    // combine: es0 waves drop w0*relu(y0+x) into LDS, es1 waves add+store.
    const float* xb = x + (size_t)b*IMG_ + (size_t)(mt*32)*HW_;
    if (es == 0) {
        #pragma unroll
        for (int f = 0; f < 2; f++) {
            int gn = f ? gn1 : gn0;
            if (gn < HW_) {
                #pragma unroll
                for (int rg = 0; rg < 4; rg++)
                    #pragma unroll
                    for (int rr = 0; rr < 4; rr++) {
                        int m = rg*8 + h*4 + rr;
                        float v = (f ? accB : accA)[rg*4 + rr] + b2[e*64 + mt*32 + m]
                                  + xb[(size_t)m*HW_ + gn];
                        P[((pg*2 + f)*32 + m)*32 + l31] = wgt * fmaxf(v, 0.f);
                    }
            }
        }
    }
    __syncthreads();
    if (es == 1) {
        float* ob = out + (size_t)b*IMG_ + (size_t)(mt*32)*HW_;
        #pragma unroll
        for (int f = 0; f < 2; f++) {
            int gn = f ? gn1 : gn0;
            if (gn < HW_) {
                #pragma unroll
                for (int rg = 0; rg < 4; rg++)
                    #pragma unroll
                    for (int rr = 0; rr < 4; rr++) {
                        int m = rg*8 + h*4 + rr;
                        float v = (f ? accB : accA)[rg*4 + rr] + b2[e*64 + mt*32 + m]
                                  + xb[(size_t)m*HW_ + gn];
                        ob[(size_t)m*HW_ + gn] = wgt * fmaxf(v, 0.f)
                                                 + P[((pg*2 + f)*32 + m)*32 + l31];
                    }
            }
        }
    }
}

extern "C" void kernel_launch(void* const* d_in, const int* in_sizes, int n_in,
                              void* d_out, int out_size, void* d_ws, size_t ws_size,
                              hipStream_t stream) {
    const float* x   = (const float*)d_in[0];
    const float* gw  = (const float*)d_in[1];
    const float* gb  = (const float*)d_in[2];
    const float* w1  = (const float*)d_in[3];
    const float* s1  = (const float*)d_in[4];
    const float* b1  = (const float*)d_in[5];
    const float* w2  = (const float*)d_in[6];
    const float* s2  = (const float*)d_in[7];
    const float* b2  = (const float*)d_in[8];
    float* out = (float*)d_out;
    float* dw  = out + (size_t)BATCH * IMG_;   // dense_w region of d_out (f32)

    (void)d_ws; (void)ws_size;                 // zero d_ws usage (R1/R2 aborts)

    hipLaunchKernelGGL(prep_kernel, dim3(2304 + 3136), dim3(256), 0, stream,
                       x, w1, s1, w2, s2);
    hipLaunchKernelGGL(gate_fin_kernel, dim3(BATCH), dim3(64), 0, stream, gw, gb, dw);
    hipLaunchKernelGGL(conv1_kernel, dim3(CGRID), dim3(512), 0, stream, b1);
    hipLaunchKernelGGL(conv2_kernel, dim3(CGRID), dim3(512), 0, stream, x, b2, out);
}

// Round 14
// 213.185 us; speedup vs baseline: 1.7561x; 1.2215x over previous
//
#include <hip/hip_runtime.h>

// ResNetBlock_MoE: B=64,C=64,H=W=56,E=8,TOPK=2. f32 in / f32 out.
// out = sum_k w_k*relu(bn2(conv2(relu(bn1(conv1(x,e)))))+x), plus dense_w.
//
// R25: R23/R24 falsified the occupancy lever (A-from-global: VGPR=48, no
// spill, Occ flat, conv2 66->78 — extra L2 A traffic beats the LDS freed).
// Revert to R21's A-in-LDS structure (best: 236.2us) and cut measured
// redundancy via both-es waves (wave = 32 pos x BOTH experts):
//  - conv1: B (=x) is expert-independent -> R21's es-split waves loaded every
//    B fragment TWICE. Now 1 B load + 2 A ds_reads + 2 MFMA/step (B VGPR
//    48->24, half the load instrs).
//  - conv2: expert combine becomes register-local: 32KB LDS P round-trip,
//    2 barriers, and duplicated x-residual reads all gone. B traffic
//    unchanged (2 streams/wave, each (es,pos) loaded once).
//  - xconv: GAP summed from the LDS tile (bf16-rounded, validated in R11)
//    instead of re-reading 51MB of x.
// Keeps: zero-page offset tables (single table/wave now), SGPR plane bases,
// kq-plane activations, kq-inner slices, barrier-free loop (1 barrier),
// XCD-chunked swizzle, A-reg rotation 3, B depth 6, SGB pins, 4 launches.

#define BATCH 64
#define CH    64
#define HW_   3136            // 56*56
#define IMG_  (CH*HW_)        // 200704
#define PLANE (HW_*16)        // 50176 u16: one kq-plane [pos][ch16]
#define NE    8
#define JOBS  128
#define PWSZ  36864           // per-expert packed weights: 36*2mt*2h*32m*8j (u16)
#define NTILE 13              // ceil(3136/256) position tiles
#define BD    6               // B-prefetch depth in steps
#define CGRID (NTILE*2*BATCH) // 1664 = 8 XCDs * 208

typedef unsigned short u16;
typedef __attribute__((ext_vector_type(8))) short short8_t;   // 8 bf16 = 4 VGPR
typedef __attribute__((ext_vector_type(16))) float floatx16;  // 32x32 MFMA acc

// zero tails (never written; .bss zero-init) back the invalid-tap offsets.
// g_h tail is extended so ONE zoff = (JOBS-2b)*IMG_*2 is safe from BOTH
// stream bases (h1 reaches IMG_ further): IMG_ + 4*PLANE extra u16.
__device__ u16   g_xb[(size_t)BATCH*IMG_ + 4*PLANE];        // x bf16 [b][kq][pos][ch16]
__device__ u16   g_h[(size_t)JOBS*IMG_ + IMG_ + 4*PLANE];   // conv1 out [job][kq][pos][ch16]
__device__ u16   g_pw1[NE * PWSZ];            // packed conv1 w (bn1_s folded)
__device__ u16   g_pw2[NE * PWSZ];            // packed conv2 w (bn2_s folded)
__device__ int   g_eid[JOBS];
__device__ float g_wgt[JOBS];
__device__ float g_pool[49 * BATCH * CH];     // GAP partials [tile49][b][ch]

__device__ __forceinline__ u16 f2b(float f) {
    unsigned v; __builtin_memcpy(&v, &f, 4);
    return (u16)((v + 0x7FFFu + ((v >> 16) & 1u)) >> 16);   // RNE
}
__device__ __forceinline__ float b2f(u16 u) {
    unsigned v = (unsigned)u << 16;
    float f; __builtin_memcpy(&f, &v, 4);
    return f;
}

// ---------------- fused prep: pack + xconv (independent outputs) ------------
// grid = 2304 (pack) + 3136 (xconv) blocks of 256. No atomics, no fences.
// pack: s36 = tap*4 + kq (kq-INNER), ci = kq*16 + h*8 + j.
__global__ __launch_bounds__(256) void prep_kernel(
    const float* __restrict__ x,
    const float* __restrict__ w1, const float* __restrict__ s1,
    const float* __restrict__ w2, const float* __restrict__ s2)
{
    int bid = blockIdx.x;
    int tid = threadIdx.x;
    if (bid < 2304) {                       // ---- pack (whole block) ----
        int idx = bid * 256 + tid;          // < 589824
        int conv = idx / 294912;
        int i2 = idx - conv * 294912;
        int e = i2 / PWSZ;   int r = i2 - e * PWSZ;
        int s36 = r >> 10;   int r2 = r & 1023;
        int mt  = r2 >> 9;   int r3 = r2 & 511;
        int h   = r3 >> 8;   int r4 = r3 & 255;
        int m   = r4 >> 3;   int j  = r4 & 7;
        int tap = s36 >> 2;
        int ci  = ((s36 & 3) << 4) | (h << 3) | j;
        int M   = mt*32 + m;
        const float* w  = conv ? w2 : w1;
        const float* sc = conv ? s2 : s1;
        float v = w[((e*64 + M)*64 + ci)*9 + tap] * sc[e*64 + M];
        (conv ? g_pw2 : g_pw1)[i2] = f2b(v);
        return;
    }
    // ---- xconv: x NCHW f32 -> g_xb [kq][pos][ch16] bf16 + GAP partial ----
    __shared__ u16 T[64*66];                // [pos][ch], stride 66
    int xid = bid - 2304;
    int b = xid / 49;
    int tile = xid - b*49;
    int pos0 = tile * 64;
    int pin = tid & 63;
    int c0 = tid >> 6;                      // 0..3
    const float* xb = x + (size_t)b*IMG_ + pos0 + pin;
    #pragma unroll
    for (int i = 0; i < 16; i++) {
        int ch = c0*16 + i;
        T[pin*66 + ch] = f2b(xb[ch*HW_]);   // coalesced 256B f32 read per instr
    }
    __syncthreads();
    u16* ob = g_xb + (size_t)b*IMG_ + (size_t)pos0*16;   // within-plane offset
    #pragma unroll
    for (int i = 0; i < 16; i++) {
        int j = tid + i*256;                // 0..4095
        int kq  = j >> 10;
        int pos = (j >> 4) & 63;
        int c16 = j & 15;
        ob[(size_t)kq*PLANE + pos*16 + c16] = T[pos*66 + kq*16 + c16];
    }
    // GAP partial from the LDS tile (bf16-rounded; validated in R11 —
    // logit perturbation ~1e-3*0.05, far below logit gaps). No x re-read.
    if (tid < 64) {
        float s = 0.f;
        #pragma unroll 8
        for (int p = 0; p < 64; p++) s += b2f(T[p*66 + tid]);
        g_pool[tile*(BATCH*CH) + b*64 + tid] = s;
    }
}

// ---------------- gate finalize: pool -> logits -> top2 softmax -------------
__global__ __launch_bounds__(64) void gate_fin_kernel(
    const float* __restrict__ gw, const float* __restrict__ gb,
    float* __restrict__ dw_out)
{
    __shared__ float pooled[CH];
    __shared__ float logits[NE];
    int b = blockIdx.x, t = threadIdx.x;
    float s = 0.f;
    #pragma unroll
    for (int i = 0; i < 49; i++) s += g_pool[i*(BATCH*CH) + b*64 + t];
    pooled[t] = s * (1.f/3136.f);
    __syncthreads();
    if (t < NE) {
        float l = gb[t];
        for (int c = 0; c < CH; c++) l += pooled[c] * gw[t*CH + c];
        logits[t] = l;
    }
    __syncthreads();
    if (t == 0) {
        int i1 = 0; float v1 = logits[0];
        for (int e = 1; e < NE; e++) if (logits[e] > v1) { v1 = logits[e]; i1 = e; }
        int i2 = -1; float v2 = -3.4e38f;
        for (int e = 0; e < NE; e++) if (e != i1 && logits[e] > v2) { v2 = logits[e]; i2 = e; }
        float eb = __expf(v2 - v1);
        float wa = 1.f / (1.f + eb), wb = eb / (1.f + eb);
        for (int e = 0; e < NE; e++) dw_out[b*NE + e] = 0.f;
        dw_out[b*NE + i1] = wa;
        dw_out[b*NE + i2] = wb;
        g_eid[2*b] = i1; g_eid[2*b+1] = i2;
        g_wgt[2*b] = wa; g_wgt[2*b+1] = wb;
    }
}

// Single-shot A stage: both experts' mt-slice, 72KB = 4608 16B-units,
// 9 rounds of 512 threads. AL layout: [s36][es][h][m32][j8].
__device__ __forceinline__ void stageA(
    u16* AL, const u16* __restrict__ pw0, const u16* __restrict__ pw1,
    int mt, int tid)
{
    short8_t st[9];
    #pragma unroll
    for (int i = 0; i < 9; i++) {
        int u = i*512 + tid;
        int es = u >= 2304;
        int r = u - (es ? 2304 : 0);
        int s36 = r >> 6;
        int c = r & 63;
        st[i] = *(const short8_t*)((es ? pw1 : pw0) + s36*1024 + mt*512 + c*8);
    }
    #pragma unroll
    for (int i = 0; i < 9; i++) {
        int u = i*512 + tid;
        int es = u >= 2304;
        int r = u - (es ? 2304 : 0);
        int s36 = r >> 6;
        int c = r & 63;
        *(short8_t*)(AL + (s36*2 + es)*512 + c*8) = st[i];
    }
}

// Per-tap offset tables: valid -> p*32 + h*16 bytes within the kq-plane;
// invalid -> zoff (zero tail past the image array).
__device__ __forceinline__ void mkOffs(
    unsigned* off, int gn, int y, int xc, int h, unsigned zoff)
{
    #pragma unroll
    for (int tap = 0; tap < 9; tap++) {
        int dy = tap/3 - 1, dx = tap - (tap/3)*3 - 1;
        int p = gn + dy*56 + dx;
        bool vld = ((unsigned)(y + dy) < 56u) && ((unsigned)(xc + dx) < 56u);
        off[tap] = vld ? (unsigned)(p*32 + h*16) : zoff;
    }
}
#define LOADB(bk, off) (*(const short8_t*)((bk) + (off)))

// ---------------- conv1 + bn1 + relu -> g_h ---------------------------------
// Both-es waves: wave = 32 positions x BOTH experts (B shared: x is
// expert-independent -> 1 B load feeds 2 MFMAs). 8 waves cover 256 pos.
// 1D grid 1664, XCD-chunked decode: L = (wg&7)*208 + wg/8.
__global__ __launch_bounds__(512, 4) void conv1_kernel(const float* __restrict__ b1)
{
    __shared__ u16 AL[36864];           // 72KB, staged once
    int wg = blockIdx.x;
    int L  = (wg & 7) * (CGRID/8) + (wg >> 3);
    int b  = L / 26;
    int r  = L - b*26;
    int tile = r >> 1;
    int mt   = r & 1;
    int e0 = g_eid[2*b], e1 = g_eid[2*b+1];
    int tid = threadIdx.x;
    int lane = tid & 63, pg = tid >> 6;  // 8 position groups of 32
    int l31 = lane & 31, h = lane >> 5;
    int gn = tile*256 + pg*32 + l31;     // may be >= 3136 (tail tile)
    int y = gn/56, xc = gn - y*56;
    const char* base = (const char*)(g_xb + (size_t)b*IMG_);
    const char* bk0 = base;                      // uniform SGPR plane bases
    const char* bk1 = base + PLANE*2;
    const char* bk2 = base + 2*PLANE*2;
    const char* bk3 = base + 3*PLANE*2;
    unsigned zoff = (unsigned)((size_t)(BATCH - b)*IMG_*2);
    const u16* pw0 = g_pw1 + e0*PWSZ;
    const u16* pw1 = g_pw1 + e1*PWSZ;
    int aOff0 = h*256 + l31*8;           // es0 fragment, + s*1024
    int aOff1 = 512 + h*256 + l31*8;     // es1 fragment

    unsigned off[9];
    mkOffs(off, gn, y, xc, h, zoff);

    floatx16 acc0 = {}, acc1 = {};       // expert 0 / expert 1
    short8_t B[BD];
    #pragma unroll
    for (int s = 0; s < BD; s++) {       // kq-inner: bk=(s&3), tap=s>>2
        const char* bk = (s&3)==0 ? bk0 : (s&3)==1 ? bk1 : (s&3)==2 ? bk2 : bk3;
        B[s] = LOADB(bk, off[s >> 2]);
    }
    stageA(AL, pw0, pw1, mt, tid);
    __syncthreads();                     // the ONLY barrier

    short8_t Ar0[3], Ar1[3];             // A rotation depth 3, both experts
    #pragma unroll
    for (int i = 0; i < 3; i++) {
        Ar0[i] = *(const short8_t*)(AL + i*1024 + aOff0);
        Ar1[i] = *(const short8_t*)(AL + i*1024 + aOff1);
    }

    #pragma unroll
    for (int s = 0; s < 36; s++) {
        short8_t bb = B[s % BD];         // capture BEFORE refill
        int sp = s + BD;
        if (sp < 36) {
            const char* bk = (sp&3)==0 ? bk0 : (sp&3)==1 ? bk1 : (sp&3)==2 ? bk2 : bk3;
            B[s % BD] = LOADB(bk, off[sp >> 2]);
        }
        short8_t a0 = Ar0[s % 3], a1 = Ar1[s % 3];
        if (s + 3 < 36) {
            Ar0[s % 3] = *(const short8_t*)(AL + (s+3)*1024 + aOff0);
            Ar1[s % 3] = *(const short8_t*)(AL + (s+3)*1024 + aOff1);
        }
        acc0 = __builtin_amdgcn_mfma_f32_32x32x16_bf16(a0, bb, acc0, 0, 0, 0);
        acc1 = __builtin_amdgcn_mfma_f32_32x32x16_bf16(a1, bb, acc1, 0, 0, 0);
        if (sp < 36)     __builtin_amdgcn_sched_group_barrier(0x020, 1, 0);
        if (s + 3 < 36)  __builtin_amdgcn_sched_group_barrier(0x100, 2, 0);
        __builtin_amdgcn_sched_group_barrier(0x008, 2, 0);
    }

    // epilogue -> both h streams; [kq][pos][ch16]: kq = mt*2 + (rg>>1)
    if (gn < HW_) {
        u16* hb0 = g_h + (size_t)(2*b)*IMG_;
        u16* hb1 = hb0 + IMG_;
        #pragma unroll
        for (int rg = 0; rg < 4; rg++) {
            union { u16 u[4]; uint2 v; } t0, t1;
            #pragma unroll
            for (int rr = 0; rr < 4; rr++) {
                int m = rg*8 + h*4 + rr;       // D row = (reg&3)+8*(reg>>2)+4*h
                t0.u[rr] = f2b(fmaxf(acc0[rg*4 + rr] + b1[e0*64 + mt*32 + m], 0.f));
                t1.u[rr] = f2b(fmaxf(acc1[rg*4 + rr] + b1[e1*64 + mt*32 + m], 0.f));
            }
            int kq = mt*2 + (rg >> 1);
            size_t o = (size_t)kq*PLANE + (size_t)gn*16 + (rg & 1)*8 + h*4;
            *(uint2*)(hb0 + o) = t0.v;
            *(uint2*)(hb1 + o) = t1.v;
        }
    }
}

// ---------------- conv2 + bn2 + residual, in-register combine ---------------
// Both-es waves: wave = 32 positions x both experts; combine is register-
// local (no LDS P, no combine barriers, single x-residual read).
__global__ __launch_bounds__(512, 4) void conv2_kernel(
    const float* __restrict__ x, const float* __restrict__ b2,
    float* __restrict__ out)
{
    __shared__ u16 AL[36864];           // 72KB A tile (only LDS use)
    int wg = blockIdx.x;
    int L  = (wg & 7) * (CGRID/8) + (wg >> 3);
    int b  = L / 26;                    // SAME b->XCD map as conv1 (h L2 reuse)
    int r  = L - b*26;
    int tile = (NTILE-1) - (r >> 1);    // tile-LIFO within b (newest h first)
    int mt   = r & 1;
    int e0 = g_eid[2*b], e1 = g_eid[2*b+1];
    float w0 = g_wgt[2*b], w1w = g_wgt[2*b+1];
    int tid = threadIdx.x;
    int lane = tid & 63, pg = tid >> 6;
    int l31 = lane & 31, h = lane >> 5;
    int gn = tile*256 + pg*32 + l31;
    int y = gn/56, xc = gn - y*56;
    const char* baseA = (const char*)(g_h + (size_t)(2*b)*IMG_);     // h0
    const char* baseB = (const char*)(g_h + (size_t)(2*b + 1)*IMG_); // h1
    const char* bkA0 = baseA;
    const char* bkA1 = baseA + PLANE*2;
    const char* bkA2 = baseA + 2*PLANE*2;
    const char* bkA3 = baseA + 3*PLANE*2;
    const char* bkB0 = baseB;
    const char* bkB1 = baseB + PLANE*2;
    const char* bkB2 = baseB + 2*PLANE*2;
    const char* bkB3 = baseB + 3*PLANE*2;
    // one zoff safe from BOTH bases (g_h tail extended by IMG_+4*PLANE u16)
    unsigned zoff = (unsigned)((size_t)(JOBS - 2*b)*IMG_*2);
    const u16* pw0 = g_pw2 + e0*PWSZ;
    const u16* pw1 = g_pw2 + e1*PWSZ;
    int aOff0 = h*256 + l31*8;
    int aOff1 = 512 + h*256 + l31*8;

    unsigned off[9];                    // single table: both streams share it
    mkOffs(off, gn, y, xc, h, zoff);

    floatx16 acc0 = {}, acc1 = {};
    short8_t B0[BD], B1[BD];            // h0 / h1 streams
    #pragma unroll
    for (int s = 0; s < BD; s++) {
        unsigned o = off[s >> 2];
        const char* bA = (s&3)==0 ? bkA0 : (s&3)==1 ? bkA1 : (s&3)==2 ? bkA2 : bkA3;
        const char* bB = (s&3)==0 ? bkB0 : (s&3)==1 ? bkB1 : (s&3)==2 ? bkB2 : bkB3;
        B0[s] = LOADB(bA, o);
        B1[s] = LOADB(bB, o);
    }
    stageA(AL, pw0, pw1, mt, tid);
    __syncthreads();                    // the ONLY barrier

    short8_t Ar0[3], Ar1[3];
    #pragma unroll
    for (int i = 0; i < 3; i++) {
        Ar0[i] = *(const short8_t*)(AL + i*1024 + aOff0);
        Ar1[i] = *(const short8_t*)(AL + i*1024 + aOff1);
    }

    #pragma unroll
    for (int s = 0; s < 36; s++) {
        short8_t bb0 = B0[s % BD];      // capture BEFORE refill
        short8_t bb1 = B1[s % BD];
        int sp = s + BD;
        if (sp < 36) {
            unsigned o = off[sp >> 2];
            const char* bA = (sp&3)==0 ? bkA0 : (sp&3)==1 ? bkA1 : (sp&3)==2 ? bkA2 : bkA3;
            const char* bB = (sp&3)==0 ? bkB0 : (sp&3)==1 ? bkB1 : (sp&3)==2 ? bkB2 : bkB3;
            B0[s % BD] = LOADB(bA, o);
            B1[s % BD] = LOADB(bB, o);
        }
        short8_t a0 = Ar0[s % 3], a1 = Ar1[s % 3];
        if (s + 3 < 36) {
            Ar0[s % 3] = *(const short8_t*)(AL + (s+3)*1024 + aOff0);
            Ar1[s % 3] = *(const short8_t*)(AL + (s+3)*1024 + aOff1);
        }
        acc0 = __builtin_amdgcn_mfma_f32_32x32x16_bf16(a0, bb0, acc0, 0, 0, 0);
        acc1 = __builtin_amdgcn_mfma_f32_32x32x16_bf16(a1, bb1, acc1, 0, 0, 0);
        if (sp < 36)     __builtin_amdgcn_sched_group_barrier(0x020, 2, 0);
        if (s + 3 < 36)  __builtin_amdgcn_sched_group_barrier(0x100, 2, 0);
        __builtin_amdgcn_sched_group_barrier(0x008, 2, 0);
    }

    // epilogue: register-local expert combine + residual + store
    if (gn < HW_) {
        const float* xb = x + (size_t)b*IMG_ + (size_t)(mt*32)*HW_;
        float* ob = out + (size_t)b*IMG_ + (size_t)(mt*32)*HW_;
        #pragma unroll
        for (int rg = 0; rg < 4; rg++)
            #pragma unroll
            for (int rr = 0; rr < 4; rr++) {
                int m = rg*8 + h*4 + rr;
                float xres = xb[(size_t)m*HW_ + gn];
                float y0 = acc0[rg*4 + rr] + b2[e0*64 + mt*32 + m];
                float y1 = acc1[rg*4 + rr] + b2[e1*64 + mt*32 + m];
                ob[(size_t)m*HW_ + gn] = w0 * fmaxf(y0 + xres, 0.f)
                                         + w1w * fmaxf(y1 + xres, 0.f);
            }
    }
}

extern "C" void kernel_launch(void* const* d_in, const int* in_sizes, int n_in,
                              void* d_out, int out_size, void* d_ws, size_t ws_size,
                              hipStream_t stream) {
    const float* x   = (const float*)d_in[0];
    const float* gw  = (const float*)d_in[1];
    const float* gb  = (const float*)d_in[2];
    const float* w1  = (const float*)d_in[3];
    const float* s1  = (const float*)d_in[4];
    const float* b1  = (const float*)d_in[5];
    const float* w2  = (const float*)d_in[6];
    const float* s2  = (const float*)d_in[7];
    const float* b2  = (const float*)d_in[8];
    float* out = (float*)d_out;
    float* dw  = out + (size_t)BATCH * IMG_;   // dense_w region of d_out (f32)

    (void)d_ws; (void)ws_size;                 // zero d_ws usage (R1/R2 aborts)

    hipLaunchKernelGGL(prep_kernel, dim3(2304 + 3136), dim3(256), 0, stream,
                       x, w1, s1, w2, s2);
    hipLaunchKernelGGL(gate_fin_kernel, dim3(BATCH), dim3(64), 0, stream, gw, gb, dw);
    hipLaunchKernelGGL(conv1_kernel, dim3(CGRID), dim3(512), 0, stream, b1);
    hipLaunchKernelGGL(conv2_kernel, dim3(CGRID), dim3(512), 0, stream, x, b2, out);
}